// Round 9
// baseline (155.431 us; speedup 1.0000x reference)
//
#include <hip/hip_runtime.h>

typedef short bf16x8 __attribute__((ext_vector_type(8)));
typedef float f32x4  __attribute__((ext_vector_type(4)));

#define CAP 12

// ws layout (bytes)
#define WS_LOSS 0
#define WS_DONE 8
#define WS_EN   64       // 1024 f32 codebook norms = 4096 B
#define WS_EBF  4160     // 1024*64 bf16 (permuted) = 131072 B

// dynamic LDS carve (bytes) — 143 KB, 1 block/CU (16 waves = 4/SIMD)
#define L_EBF    0        // 131072
#define L_MARG   131072   // 256*4 = 1024
#define L_CCNT   132096   // 1024
#define L_KCH    133120   // 1024
#define L_CSLOT  134144   // 256*CAP*4 = 12288
#define L_TOTAL  146432

__device__ __forceinline__ unsigned short f2bf(float f) {
    unsigned u = __float_as_uint(f);
    return (unsigned short)((u + 0x7fffu + ((u >> 16) & 1u)) >> 16);  // RTNE
}

// numpy pairwise sum (n=64): 8 accumulators, ((r0+r1)+(r2+r3))+((r4+r5)+(r6+r7)).
__device__ __forceinline__ float np_pairwise_sumsq64(const float* a) {
    float r[8];
    #pragma unroll
    for (int j = 0; j < 8; ++j) r[j] = __fmul_rn(a[j], a[j]);
    #pragma unroll
    for (int i = 8; i < 64; i += 8)
        #pragma unroll
        for (int j = 0; j < 8; ++j)
            r[j] = __fadd_rn(r[j], __fmul_rn(a[i + j], a[i + j]));
    return __fadd_rn(
        __fadd_rn(__fadd_rn(r[0], r[1]), __fadd_rn(r[2], r[3])),
        __fadd_rn(__fadd_rn(r[4], r[5]), __fadd_rn(r[6], r[7])));
}

// K1: bf16 codebook in MFMA-B-fragment-permuted layout + per-code exact fp32
// norms (bit-identical np_pairwise order) + zero loss/done.
// ebf[tile(64)][chunk j(8)][row r(16)][8 bf16], code = tile*16+r.
__global__ __launch_bounds__(256) void prep_kernel(
    const float* __restrict__ emb, unsigned short* __restrict__ ebf,
    float* __restrict__ en_t,
    float* __restrict__ loss, int* __restrict__ done)
{
    int k = blockIdx.x * 256 + threadIdx.x;
    if (k == 0) { *loss = 0.0f; *done = 0; }
    if (k < 1024) {
        float e[64];
        #pragma unroll
        for (int l = 0; l < 64; ++l) e[l] = emb[k * 64 + l];
        en_t[k] = np_pairwise_sumsq64(e);      // bit-exact numpy enorm
        int tile = k >> 4, r = k & 15;
        #pragma unroll
        for (int j = 0; j < 8; ++j) {
            bf16x8 v;
            #pragma unroll
            for (int m = 0; m < 8; ++m) v[m] = (short)f2bf(e[j * 8 + m]);
            *(bf16x8*)(ebf + tile * 1024 + j * 128 + r * 8) = v;
        }
    }
}

// K2: fused VQ — pure-TLP experiment at constant instruction count.
// 1024 thr (16 waves = 4/SIMD), 256 pos/block, grid 256. Wave = 16 positions
// x ALL 1024 codes (pure pos-split: per-CU MFMA/ds/VALU totals IDENTICAL to
// the 512-thr R8 build; per-wave serial chains halved, wave pool doubled).
// Evidence: R8 showed ~80% issue-idle at 2 waves/SIMD with all in-wave ILP
// levers exhausted -> stalls must be covered by MORE WAVES. R3's failed
// occupancy test was confounded (4x A redundancy + 64-VGPR remat codegen);
// this one is clean: small working set, depth-4 rings, no z-hoist.
__global__ __launch_bounds__(1024, 4)
void vq_kernel(
    const float* __restrict__ ze, const float* __restrict__ emb,
    const unsigned short* __restrict__ ebf, const float* __restrict__ en_t,
    float* __restrict__ out_zq, float* __restrict__ out_idxf,
    float* __restrict__ loss, int* __restrict__ done,
    float* __restrict__ out_loss)
{
    extern __shared__ char smem[];
    unsigned short* ebf_l = (unsigned short*)(smem + L_EBF);
    float*          marg_l= (float*)(smem + L_MARG);
    int*            ccnt  = (int*)(smem + L_CCNT);
    int*            kch   = (int*)(smem + L_KCH);
    int*            cslot = (int*)(smem + L_CSLOT);

    const int t = threadIdx.x;
    const int n0 = blockIdx.x * 256;
    const int gbase = (n0 >> 12) * 262144 + (n0 & 4095);

    // ---- stage codebook -> LDS (1024 thr x 8 x 16B vector copies) ----
    {
        const bf16x8* src = (const bf16x8*)ebf;
        bf16x8* dst = (bf16x8*)ebf_l;
        #pragma unroll 8
        for (int i = 0; i < 8; ++i) dst[t + i * 1024] = src[t + i * 1024];
    }

    // ---- A-fragments from global ze (L3-hot) + folded margin ----
    const int wv = t >> 6, lane = t & 63;
    const int r = lane & 15, q = lane >> 4;
    const int wp = wv * 16;                    // wave's 16 positions
    bf16x8 a0, a1;
    float sm = 0.0f;
    {
        const float* zb = ze + gbase + wp + r;
        #pragma unroll
        for (int j = 0; j < 8; ++j) {
            const float v0 = zb[(q * 8 + j) * 4096];
            const float v1 = zb[(32 + q * 8 + j) * 4096];
            a0[j] = (short)f2bf(v0);
            a1[j] = (short)f2bf(v1);
            sm += fabsf(v0) + fabsf(v1);
        }
    }
    // margin: reduce |z|-partials over the 4 q-lane groups; q==0 lanes publish
    {
        float s = sm;
        s += __shfl_xor(s, 16, 64);
        s += __shfl_xor(s, 32, 64);
        if (q == 0) marg_l[wp + r] = 1.67e-5f * s + 2.0e-4f;
    }
    if (t < 256) ccnt[t] = 0;
    __syncthreads();   // staging + marg + ccnt visible

    const unsigned short* bptr = ebf_l + q * 128 + r * 8;

    // ---- pass 1: per-row max of c = z.e over ALL 1024 codes (64 tiles) ----
    float rm[4];
    #pragma unroll
    for (int i = 0; i < 4; ++i) rm[i] = -1e30f;
    {
        bf16x8 pb0[4], pb1[4];
        #pragma unroll
        for (int i = 0; i < 4; ++i) {
            pb0[i] = *(const bf16x8*)(bptr + i * 1024);
            pb1[i] = *(const bf16x8*)(bptr + i * 1024 + 512);
        }
        #pragma unroll 4
        for (int tile = 0; tile < 64; ++tile) {
            bf16x8 b0 = pb0[tile & 3], b1 = pb1[tile & 3];
            int nt = tile + 4; if (nt > 63) nt = 63;
            pb0[tile & 3] = *(const bf16x8*)(bptr + nt * 1024);
            pb1[tile & 3] = *(const bf16x8*)(bptr + nt * 1024 + 512);
            f32x4 c = {0.f, 0.f, 0.f, 0.f};
            c = __builtin_amdgcn_mfma_f32_16x16x32_bf16(a0, b0, c, 0, 0, 0);
            c = __builtin_amdgcn_mfma_f32_16x16x32_bf16(a1, b1, c, 0, 0, 0);
            #pragma unroll
            for (int i = 0; i < 4; ++i)
                rm[i] = fmaxf(rm[i], c[i]);
        }
    }
    // in-wave rowmax: reduce over the 16 code-lanes (no LDS, no barrier)
    #pragma unroll
    for (int j = 0; j < 4; ++j) {
        float v = rm[j];
        v = fmaxf(v, __shfl_xor(v, 1, 16));
        v = fmaxf(v, __shfl_xor(v, 2, 16));
        v = fmaxf(v, __shfl_xor(v, 4, 16));
        v = fmaxf(v, __shfl_xor(v, 8, 16));
        rm[j] = v;
    }
    // threshold: candidate iff c >= maxc - marg/2
    float thr[4];
    #pragma unroll
    for (int j = 0; j < 4; ++j)
        thr[j] = rm[j] - 0.5f * marg_l[wp + q * 4 + j];

    // ---- pass 2: collect candidates (wave-private rows; LDS atomics) ----
    {
        bf16x8 pb0[4], pb1[4];
        #pragma unroll
        for (int i = 0; i < 4; ++i) {
            pb0[i] = *(const bf16x8*)(bptr + i * 1024);
            pb1[i] = *(const bf16x8*)(bptr + i * 1024 + 512);
        }
        #pragma unroll 4
        for (int tile = 0; tile < 64; ++tile) {
            bf16x8 b0 = pb0[tile & 3], b1 = pb1[tile & 3];
            int nt = tile + 4; if (nt > 63) nt = 63;
            pb0[tile & 3] = *(const bf16x8*)(bptr + nt * 1024);
            pb1[tile & 3] = *(const bf16x8*)(bptr + nt * 1024 + 512);
            const int code = tile * 16 + r;
            f32x4 c = {0.f, 0.f, 0.f, 0.f};
            c = __builtin_amdgcn_mfma_f32_16x16x32_bf16(a0, b0, c, 0, 0, 0);
            c = __builtin_amdgcn_mfma_f32_16x16x32_bf16(a1, b1, c, 0, 0, 0);
            #pragma unroll
            for (int i = 0; i < 4; ++i) {
                if (c[i] >= thr[i]) {
                    const int pp = wp + q * 4 + i;
                    const int ci = atomicAdd(&ccnt[pp], 1);
                    if (ci < CAP) cslot[pp * CAP + ci] = code;
                }
            }
        }
    }
    __syncthreads();

    // ---- exact fp32 numpy rescore, 4 threads/position (candidate-strided);
    // enorm from precomputed table; dot in sequential numpy sgemm order.
    {
        const int p = t >> 2, cl = t & 3;
        int cnt = ccnt[p]; if (cnt > CAP) cnt = CAP;
        float z[64];
        const float* zp = ze + gbase + p;
        #pragma unroll
        for (int l = 0; l < 64; ++l) z[l] = zp[l * 4096];   // L3-hot, verbatim
        const float znorm = np_pairwise_sumsq64(z);
        float best = 1e30f; int bk = 1 << 20;
        for (int c = cl; c < cnt; c += 4) {
            const int k = cslot[p * CAP + c];
            const float4* er = (const float4*)(emb + k * 64);
            float acc = 0.0f;
            #pragma unroll
            for (int jj = 0; jj < 16; ++jj) {
                const float4 v = er[jj];
                acc = fmaf(z[4 * jj + 0], v.x, acc);
                acc = fmaf(z[4 * jj + 1], v.y, acc);
                acc = fmaf(z[4 * jj + 2], v.z, acc);
                acc = fmaf(z[4 * jj + 3], v.w, acc);
            }
            const float sc = __fsub_rn(__fadd_rn(znorm, en_t[k]), __fmul_rn(2.0f, acc));
            if (sc < best || (sc == best && k < bk)) { best = sc; bk = k; }
        }
        // lex-(score,k) butterfly merge within the 4-lane position group
        #pragma unroll
        for (int m = 1; m < 4; m <<= 1) {
            const float ob = __shfl_xor(best, m, 4);
            const int   ok = __shfl_xor(bk, m, 4);
            if (ob < best || (ob == best && ok < bk)) { best = ob; bk = ok; }
        }
        if (cl == 0) {
            kch[p] = bk;
            out_idxf[n0 + p] = (float)bk;
        }
    }
    __syncthreads();

    // ---- epilogue: 1024 threads, dims split (h = t>>8, 16 dims each).
    // Batch all loads first (er + zp), then store/accumulate.
    {
        const int p = t & 255, h = t >> 8;
        const int bk = kch[p];
        const float* er = emb + bk * 64 + h * 16;
        const float* zp = ze + gbase + p + (h * 16) * 4096;
        float* op = out_zq + gbase + p + (h * 16) * 4096;
        float ev[16], zv[16];
        #pragma unroll
        for (int j = 0; j < 16; ++j) ev[j] = er[j];
        #pragma unroll
        for (int j = 0; j < 16; ++j) zv[j] = zp[j * 4096];
        float ls = 0.0f;
        #pragma unroll
        for (int j = 0; j < 16; ++j) {
            op[j * 4096] = ev[j];
            const float d = ev[j] - zv[j];
            ls = fmaf(d, d, ls);
        }
        #pragma unroll
        for (int off = 32; off > 0; off >>= 1) ls += __shfl_down(ls, off, 64);
        if (lane == 0) atomicAdd(loss, ls);
    }

    // ---- last block finalizes loss (device-scope atomics) ----
    __syncthreads();
    if (t == 0) {
        __threadfence();
        int old = atomicAdd(done, 1);
        if (old == (int)gridDim.x - 1) {
            __threadfence();
            float total = atomicAdd(loss, 0.0f);   // coherent read
            *out_loss = 1.25f * total / 4194304.0f;
        }
    }
}

extern "C" void kernel_launch(void* const* d_in, const int* in_sizes, int n_in,
                              void* d_out, int out_size, void* d_ws, size_t ws_size,
                              hipStream_t stream)
{
    const float* ze  = (const float*)d_in[0];   // (16,64,64,64) fp32
    const float* emb = (const float*)d_in[1];   // (1024,64) fp32
    float* out = (float*)d_out;
    float* out_zq   = out;                 // 4194304
    float* out_loss = out + 4194304;       // 1
    float* out_idxf = out + 4194305;       // 65536

    char* w = (char*)d_ws;
    float*          ws_loss = (float*)(w + WS_LOSS);
    int*            ws_done = (int*)(w + WS_DONE);
    float*          ws_en   = (float*)(w + WS_EN);
    unsigned short* ebf     = (unsigned short*)(w + WS_EBF);

    // allow >64KB dynamic LDS (no-op if already permitted)
    static bool attr_set = false;
    if (!attr_set) {
        hipFuncSetAttribute((const void*)vq_kernel,
                            hipFuncAttributeMaxDynamicSharedMemorySize, L_TOTAL);
        attr_set = true;
    }

    prep_kernel<<<4, 256, 0, stream>>>(emb, ebf, ws_en, ws_loss, ws_done);
    vq_kernel<<<256, 1024, L_TOTAL, stream>>>(ze, emb, ebf, ws_en, out_zq,
                                              out_idxf, ws_loss, ws_done, out_loss);
}

// Round 10
// 149.754 us; speedup vs baseline: 1.0379x; 1.0379x over previous
//
#include <hip/hip_runtime.h>

typedef short bf16x8 __attribute__((ext_vector_type(8)));
typedef float f32x4  __attribute__((ext_vector_type(4)));

#define CAP 12

// ws layout (bytes)
#define WS_LOSS 0
#define WS_DONE 8
#define WS_EN   64       // 1024 f32 codebook norms = 4096 B
#define WS_EBF  4160     // 1024*64 bf16 (permuted) = 131072 B

// out_zq scratch carve (ints), overwritten by epilogue at the end:
//   slot_g: 65536*12 ints = 786432
//   cnt_g : 65536 ints at offset 786432
#define SLOT_OFF 0
#define CNT_OFF  786432

// dist kernel LDS carve (bytes)
#define LD_EBF    0        // 131072
#define LD_MARG   131072   // 1024
#define LD_CCNT   132096   // 1024
#define LD_CSLOT  133120   // 256*CAP*4 = 12288
#define LD_TOTAL  145408

__device__ __forceinline__ unsigned short f2bf(float f) {
    unsigned u = __float_as_uint(f);
    return (unsigned short)((u + 0x7fffu + ((u >> 16) & 1u)) >> 16);  // RTNE
}

// numpy pairwise sum (n=64): 8 accumulators, ((r0+r1)+(r2+r3))+((r4+r5)+(r6+r7)).
__device__ __forceinline__ float np_pairwise_sumsq64(const float* a) {
    float r[8];
    #pragma unroll
    for (int j = 0; j < 8; ++j) r[j] = __fmul_rn(a[j], a[j]);
    #pragma unroll
    for (int i = 8; i < 64; i += 8)
        #pragma unroll
        for (int j = 0; j < 8; ++j)
            r[j] = __fadd_rn(r[j], __fmul_rn(a[i + j], a[i + j]));
    return __fadd_rn(
        __fadd_rn(__fadd_rn(r[0], r[1]), __fadd_rn(r[2], r[3])),
        __fadd_rn(__fadd_rn(r[4], r[5]), __fadd_rn(r[6], r[7])));
}

// K1: bf16 codebook in MFMA-B-fragment-permuted layout + per-code exact fp32
// norms + zero loss/done. ebf[tile(64)][chunk j(8)][row r(16)][8 bf16].
__global__ __launch_bounds__(256) void prep_kernel(
    const float* __restrict__ emb, unsigned short* __restrict__ ebf,
    float* __restrict__ en_t,
    float* __restrict__ loss, int* __restrict__ done)
{
    int k = blockIdx.x * 256 + threadIdx.x;
    if (k == 0) { *loss = 0.0f; *done = 0; }
    if (k < 1024) {
        float e[64];
        #pragma unroll
        for (int l = 0; l < 64; ++l) e[l] = emb[k * 64 + l];
        en_t[k] = np_pairwise_sumsq64(e);      // bit-exact numpy enorm
        int tile = k >> 4, r = k & 15;
        #pragma unroll
        for (int j = 0; j < 8; ++j) {
            bf16x8 v;
            #pragma unroll
            for (int m = 0; m < 8; ++m) v[m] = (short)f2bf(e[j * 8 + m]);
            *(bf16x8*)(ebf + tile * 1024 + j * 128 + r * 8) = v;
        }
    }
}

// K2 dist: phase-split diagnostic — R8's staging+A-build+pass1+pass2 verbatim,
// dumping candidates to global scratch (carved from out_zq, which the
// epilogue later fully overwrites). 256 blocks x 512 thr, wave = 32 pos x
// all 1024 codes, depth-8 B-prefetch rings.
__global__ __launch_bounds__(512, 2)
void dist_kernel(
    const float* __restrict__ ze, const unsigned short* __restrict__ ebf,
    int* __restrict__ slot_g, int* __restrict__ cnt_g)
{
    extern __shared__ char smem[];
    unsigned short* ebf_l = (unsigned short*)(smem + LD_EBF);
    float*          marg_l= (float*)(smem + LD_MARG);
    int*            ccnt  = (int*)(smem + LD_CCNT);
    int*            cslot = (int*)(smem + LD_CSLOT);

    const int t = threadIdx.x;
    const int n0 = blockIdx.x * 256;
    const int gbase = (n0 >> 12) * 262144 + (n0 & 4095);

    // ---- stage codebook -> LDS (512 thr x 16 x 16B vector copies) ----
    {
        const bf16x8* src = (const bf16x8*)ebf;
        bf16x8* dst = (bf16x8*)ebf_l;
        #pragma unroll 16
        for (int i = 0; i < 16; ++i) dst[t + i * 512] = src[t + i * 512];
    }

    // ---- A-fragments from global ze (L3-hot) + folded margin ----
    const int wv = t >> 6, lane = t & 63;
    const int r = lane & 15, q = lane >> 4;
    const int wp = wv * 32;
    bf16x8 a[2][2];
    float sm[2] = {0.f, 0.f};
    #pragma unroll
    for (int rg = 0; rg < 2; ++rg) {
        const float* zb = ze + gbase + wp + rg * 16 + r;
        #pragma unroll
        for (int j = 0; j < 8; ++j) {
            const float v0 = zb[(q * 8 + j) * 4096];
            const float v1 = zb[(32 + q * 8 + j) * 4096];
            a[rg][0][j] = (short)f2bf(v0);
            a[rg][1][j] = (short)f2bf(v1);
            sm[rg] += fabsf(v0) + fabsf(v1);
        }
    }
    #pragma unroll
    for (int rg = 0; rg < 2; ++rg) {
        float s = sm[rg];
        s += __shfl_xor(s, 16, 64);
        s += __shfl_xor(s, 32, 64);
        if (q == 0) marg_l[wp + rg * 16 + r] = 1.67e-5f * s + 2.0e-4f;
    }
    if (t < 256) ccnt[t] = 0;
    __syncthreads();

    const unsigned short* bptr = ebf_l + q * 128 + r * 8;

    // ---- pass 1: per-row max over ALL 1024 codes (64 tiles) ----
    float rm[8];
    #pragma unroll
    for (int i = 0; i < 8; ++i) rm[i] = -1e30f;
    {
        bf16x8 pb0[8], pb1[8];
        #pragma unroll
        for (int i = 0; i < 8; ++i) {
            pb0[i] = *(const bf16x8*)(bptr + i * 1024);
            pb1[i] = *(const bf16x8*)(bptr + i * 1024 + 512);
        }
        #pragma unroll 8
        for (int tile = 0; tile < 64; ++tile) {
            bf16x8 b0 = pb0[tile & 7], b1 = pb1[tile & 7];
            int nt = tile + 8; if (nt > 63) nt = 63;
            pb0[tile & 7] = *(const bf16x8*)(bptr + nt * 1024);
            pb1[tile & 7] = *(const bf16x8*)(bptr + nt * 1024 + 512);
            #pragma unroll
            for (int rg = 0; rg < 2; ++rg) {
                f32x4 c = {0.f, 0.f, 0.f, 0.f};
                c = __builtin_amdgcn_mfma_f32_16x16x32_bf16(a[rg][0], b0, c, 0, 0, 0);
                c = __builtin_amdgcn_mfma_f32_16x16x32_bf16(a[rg][1], b1, c, 0, 0, 0);
                #pragma unroll
                for (int i = 0; i < 4; ++i)
                    rm[rg * 4 + i] = fmaxf(rm[rg * 4 + i], c[i]);
            }
        }
    }
    #pragma unroll
    for (int j = 0; j < 8; ++j) {
        float v = rm[j];
        v = fmaxf(v, __shfl_xor(v, 1, 16));
        v = fmaxf(v, __shfl_xor(v, 2, 16));
        v = fmaxf(v, __shfl_xor(v, 4, 16));
        v = fmaxf(v, __shfl_xor(v, 8, 16));
        rm[j] = v;
    }
    float thr[8];
    #pragma unroll
    for (int j = 0; j < 8; ++j) {
        const int row = wp + (j >> 2) * 16 + q * 4 + (j & 3);
        thr[j] = rm[j] - 0.5f * marg_l[row];
    }

    // ---- pass 2: collect candidates ----
    {
        bf16x8 pb0[8], pb1[8];
        #pragma unroll
        for (int i = 0; i < 8; ++i) {
            pb0[i] = *(const bf16x8*)(bptr + i * 1024);
            pb1[i] = *(const bf16x8*)(bptr + i * 1024 + 512);
        }
        #pragma unroll 8
        for (int tile = 0; tile < 64; ++tile) {
            bf16x8 b0 = pb0[tile & 7], b1 = pb1[tile & 7];
            int nt = tile + 8; if (nt > 63) nt = 63;
            pb0[tile & 7] = *(const bf16x8*)(bptr + nt * 1024);
            pb1[tile & 7] = *(const bf16x8*)(bptr + nt * 1024 + 512);
            const int code = tile * 16 + r;
            #pragma unroll
            for (int rg = 0; rg < 2; ++rg) {
                f32x4 c = {0.f, 0.f, 0.f, 0.f};
                c = __builtin_amdgcn_mfma_f32_16x16x32_bf16(a[rg][0], b0, c, 0, 0, 0);
                c = __builtin_amdgcn_mfma_f32_16x16x32_bf16(a[rg][1], b1, c, 0, 0, 0);
                #pragma unroll
                for (int i = 0; i < 4; ++i) {
                    if (c[i] >= thr[rg * 4 + i]) {
                        const int pp = wp + rg * 16 + q * 4 + i;
                        const int ci = atomicAdd(&ccnt[pp], 1);
                        if (ci < CAP) cslot[pp * CAP + ci] = code;
                    }
                }
            }
        }
    }
    __syncthreads();

    // ---- dump candidates to global scratch ----
    if (t < 256) {
        const int P = n0 + t;
        cnt_g[P] = ccnt[t];                     // raw; rescore clamps (as fused)
        const int4* s = (const int4*)(cslot + t * CAP);
        int4* d = (int4*)(slot_g + P * CAP);
        d[0] = s[0]; d[1] = s[1]; d[2] = s[2];
    }
}

// K3 rescore: 1 thread/position, 256 blocks x 256 thr, high occupancy.
// z-reload fully coalesced (lane==pos). Exact fp32 numpy rescore + lex-(score,k).
__global__ __launch_bounds__(256, 4)
void rescore_kernel(
    const float* __restrict__ ze, const float* __restrict__ emb,
    const float* __restrict__ en_t,
    const int* __restrict__ slot_g, const int* __restrict__ cnt_g,
    float* __restrict__ out_idxf)
{
    const int P = blockIdx.x * 256 + threadIdx.x;
    int cnt = cnt_g[P]; if (cnt > CAP) cnt = CAP;
    const float* zp = ze + (P >> 12) * 262144 + (P & 4095);
    float z[64];
    #pragma unroll
    for (int l = 0; l < 64; ++l) z[l] = zp[l * 4096];   // coalesced across block
    const float znorm = np_pairwise_sumsq64(z);
    float best = 1e30f; int bk = 1 << 20;
    for (int c = 0; c < cnt; ++c) {
        const int k = slot_g[P * CAP + c];
        const float4* er = (const float4*)(emb + k * 64);
        float acc = 0.0f;
        #pragma unroll
        for (int jj = 0; jj < 16; ++jj) {
            const float4 v = er[jj];
            acc = fmaf(z[4 * jj + 0], v.x, acc);
            acc = fmaf(z[4 * jj + 1], v.y, acc);
            acc = fmaf(z[4 * jj + 2], v.z, acc);
            acc = fmaf(z[4 * jj + 3], v.w, acc);
        }
        const float sc = __fsub_rn(__fadd_rn(znorm, en_t[k]), __fmul_rn(2.0f, acc));
        if (sc < best || (sc == best && k < bk)) { best = sc; bk = k; }
    }
    out_idxf[P] = (float)bk;
}

// K4 epilogue: streaming gather/scatter + loss; finalizes loss (last block).
__global__ __launch_bounds__(512, 2)
void epi_kernel(
    const float* __restrict__ ze, const float* __restrict__ emb,
    const float* __restrict__ out_idxf,
    float* __restrict__ out_zq, float* __restrict__ loss,
    int* __restrict__ done, float* __restrict__ out_loss)
{
    const int t = threadIdx.x, lane = t & 63;
    const int n0 = blockIdx.x * 256;
    const int gbase = (n0 >> 12) * 262144 + (n0 & 4095);
    const int p = t & 255, h = t >> 8;
    const int bk = (int)out_idxf[n0 + p];
    const float* er = emb + bk * 64 + h * 32;
    const float* zp = ze + gbase + p + (h * 32) * 4096;
    float* op = out_zq + gbase + p + (h * 32) * 4096;
    float ev[32], zv[32];
    #pragma unroll
    for (int j = 0; j < 32; ++j) ev[j] = er[j];
    #pragma unroll
    for (int j = 0; j < 32; ++j) zv[j] = zp[j * 4096];
    float ls = 0.0f;
    #pragma unroll
    for (int j = 0; j < 32; ++j) {
        op[j * 4096] = ev[j];
        const float d = ev[j] - zv[j];
        ls = fmaf(d, d, ls);
    }
    #pragma unroll
    for (int off = 32; off > 0; off >>= 1) ls += __shfl_down(ls, off, 64);
    if (lane == 0) atomicAdd(loss, ls);

    __syncthreads();
    if (t == 0) {
        __threadfence();
        int old = atomicAdd(done, 1);
        if (old == (int)gridDim.x - 1) {
            __threadfence();
            float total = atomicAdd(loss, 0.0f);   // coherent read
            *out_loss = 1.25f * total / 4194304.0f;
        }
    }
}

extern "C" void kernel_launch(void* const* d_in, const int* in_sizes, int n_in,
                              void* d_out, int out_size, void* d_ws, size_t ws_size,
                              hipStream_t stream)
{
    const float* ze  = (const float*)d_in[0];   // (16,64,64,64) fp32
    const float* emb = (const float*)d_in[1];   // (1024,64) fp32
    float* out = (float*)d_out;
    float* out_zq   = out;                 // 4194304
    float* out_loss = out + 4194304;       // 1
    float* out_idxf = out + 4194305;       // 65536

    char* w = (char*)d_ws;
    float*          ws_loss = (float*)(w + WS_LOSS);
    int*            ws_done = (int*)(w + WS_DONE);
    float*          ws_en   = (float*)(w + WS_EN);
    unsigned short* ebf     = (unsigned short*)(w + WS_EBF);

    // scratch carved from out_zq (fully overwritten by epi_kernel)
    int* slot_g = (int*)out_zq + SLOT_OFF;
    int* cnt_g  = (int*)out_zq + CNT_OFF;

    // allow >64KB dynamic LDS (no-op if already permitted)
    static bool attr_set = false;
    if (!attr_set) {
        hipFuncSetAttribute((const void*)dist_kernel,
                            hipFuncAttributeMaxDynamicSharedMemorySize, LD_TOTAL);
        attr_set = true;
    }

    prep_kernel<<<4, 256, 0, stream>>>(emb, ebf, ws_en, ws_loss, ws_done);
    dist_kernel<<<256, 512, LD_TOTAL, stream>>>(ze, ebf, slot_g, cnt_g);
    rescore_kernel<<<256, 256, 0, stream>>>(ze, emb, ws_en, slot_g, cnt_g,
                                            out_idxf);
    epi_kernel<<<256, 512, 0, stream>>>(ze, emb, out_idxf, out_zq,
                                        ws_loss, ws_done, out_loss);
}